// Round 13
// baseline (296.377 us; speedup 1.0000x reference)
//
#include <hip/hip_runtime.h>
#include <hip/hip_fp16.h>

#define NN 50000
#define NE 640000
#define RB ((NN + 255) / 256)   // 196 scan blocks

#define GA_BLOCKS 781            // gemm1 first-half blocks (rows [0,24992))
#define GB_BLOCKS 782            // gemm1 second-half blocks (rows [24992,50016) clamped)
#define GB32 ((NN + 31) / 32)    // 1563 blocks for standalone gemms

#define SC_GROUPS 8              // destination-range groups (~XCDs via blockIdx%8)
#define SC_RANGE (NN / SC_GROUPS)        // 6250
#define SC_EPT 8                 // edges per thread
#define SC_CHUNK (256 * SC_EPT)          // 2048 edges per block-chunk
#define SC_CHUNKS ((NE + SC_CHUNK - 1) / SC_CHUNK)

struct __align__(8) edge_t { int r; float w; };

__device__ __forceinline__ int edge_at(const void* p, long long i, int m64) {
    if (m64) return (int)((const long long*)p)[i];
    return ((const int*)p)[i];
}

// per-block int64/int32 detection (odd words = int64 high words, zero for
// nonneg < 2^31; int32 row values are random nonzero w.h.p.)
__device__ __forceinline__ int detect_m64(const unsigned* w, int tid) {
    __shared__ int found;
    if (tid == 0) found = 0;
    __syncthreads();
    if (tid < 256 && w[2 * tid + 1] != 0u) atomicAdd(&found, 1);
    __syncthreads();
    return (found == 0) ? 1 : 0;
}

// ---- shared gemm body: 32 rows starting at row0_blk, W staged in 16 KB
// k-quarters (4 stages) -> ~7 blocks/CU co-residency. 2x8 tile per thread.
__device__ __forceinline__ void gemm32_body(const float* __restrict__ A,
                                            const float* __restrict__ W,
                                            __half* __restrict__ Th,
                                            int row0_blk, int t, float* Ws) {
    int rg = t >> 4, cg = t & 15;
    int row0 = row0_blk + rg * 2;
    const float4* a0 = (const float4*)(A + (long long)min(row0 + 0, NN - 1) * 128);
    const float4* a1 = (const float4*)(A + (long long)min(row0 + 1, NN - 1) * 128);
    float acc[2][8];
#pragma unroll
    for (int i = 0; i < 2; i++)
#pragma unroll
        for (int j = 0; j < 8; j++) acc[i][j] = 0.f;
#pragma unroll
    for (int h = 0; h < 4; h++) {        // 4 k-quarters of 32 rows (16 KB)
        __syncthreads();
#pragma unroll
        for (int i = 0; i < 4; i++)      // 1024 float4 staged by 256 thr
            ((float4*)Ws)[t + 256 * i] = ((const float4*)(W + h * 32 * 128))[t + 256 * i];
        __syncthreads();
#pragma unroll 4
        for (int k4 = 0; k4 < 8; k4++) {
            float4 av0 = a0[h * 8 + k4];
            float4 av1 = a1[h * 8 + k4];
#pragma unroll
            for (int kk = 0; kk < 4; kk++) {
                float4 w0 = *(const float4*)&Ws[(k4 * 4 + kk) * 128 + cg * 4];
                float4 w1 = *(const float4*)&Ws[(k4 * 4 + kk) * 128 + cg * 4 + 64];
                float x0 = (kk == 0) ? av0.x : (kk == 1) ? av0.y : (kk == 2) ? av0.z : av0.w;
                float x1 = (kk == 0) ? av1.x : (kk == 1) ? av1.y : (kk == 2) ? av1.z : av1.w;
                acc[0][0] += x0 * w0.x; acc[0][1] += x0 * w0.y;
                acc[0][2] += x0 * w0.z; acc[0][3] += x0 * w0.w;
                acc[0][4] += x0 * w1.x; acc[0][5] += x0 * w1.y;
                acc[0][6] += x0 * w1.z; acc[0][7] += x0 * w1.w;
                acc[1][0] += x1 * w0.x; acc[1][1] += x1 * w0.y;
                acc[1][2] += x1 * w0.z; acc[1][3] += x1 * w0.w;
                acc[1][4] += x1 * w1.x; acc[1][5] += x1 * w1.y;
                acc[1][6] += x1 * w1.z; acc[1][7] += x1 * w1.w;
            }
        }
    }
#pragma unroll
    for (int i = 0; i < 2; i++) {
        int row = row0 + i;
        if (row < NN) {
            __half2 p0 = __floats2half2_rn(acc[i][0], acc[i][1]);
            __half2 p1 = __floats2half2_rn(acc[i][2], acc[i][3]);
            __half2 p2 = __floats2half2_rn(acc[i][4], acc[i][5]);
            __half2 p3 = __floats2half2_rn(acc[i][6], acc[i][7]);
            uint2 u0; u0.x = *(unsigned*)&p0; u0.y = *(unsigned*)&p1;
            uint2 u1; u1.x = *(unsigned*)&p2; u1.y = *(unsigned*)&p3;
            *(uint2*)(Th + (long long)row * 128 + cg * 4) = u0;
            *(uint2*)(Th + (long long)row * 128 + cg * 4 + 64) = u1;
        }
    }
}

// ---- kernel A: gemm1 rows [0,24992) + XCD-localized count ----
__global__ __launch_bounds__(256) void k_gemm_count(const void* __restrict__ e,
                                                    int* __restrict__ deg,
                                                    const float* __restrict__ A,
                                                    const float* __restrict__ W,
                                                    __half* __restrict__ Th) {
    __shared__ float Ws[32 * 128];       // 16 KB
    int t = threadIdx.x;
    if (blockIdx.x >= GA_BLOCKS) {
        int m = detect_m64((const unsigned*)e, t);
        int b = blockIdx.x - GA_BLOCKS;
        int g = b & (SC_GROUPS - 1);
        int chunk = b >> 3;
        int clo = g * SC_RANGE, chi = clo + SC_RANGE;
        int base = chunk * SC_CHUNK + t;
#pragma unroll
        for (int j = 0; j < SC_EPT; j++) {
            int i = base + j * 256;
            if (i < NE) {
                int c = edge_at(e, (long long)NE + i, m);
                if (c >= clo && c < chi) atomicAdd(&deg[c], 1);
            }
        }
        return;
    }
    gemm32_body(A, W, Th, blockIdx.x * 32, t, Ws);
}

// ---- kernel B: gemm1 rows [24992,50000) + XCD-localized scatter ----
__global__ __launch_bounds__(256) void k_gemm_scatter(const void* __restrict__ e,
                                                      int* __restrict__ cursor,
                                                      edge_t* __restrict__ ew,
                                                      const float* __restrict__ dinv,
                                                      const float* __restrict__ A,
                                                      const float* __restrict__ W,
                                                      __half* __restrict__ Th) {
    __shared__ float Ws[32 * 128];       // 16 KB
    int t = threadIdx.x;
    if (blockIdx.x >= GB_BLOCKS) {
        int m = detect_m64((const unsigned*)e, t);
        int b = blockIdx.x - GB_BLOCKS;
        int g = b & (SC_GROUPS - 1);
        int chunk = b >> 3;
        int clo = g * SC_RANGE, chi = clo + SC_RANGE;
        int base = chunk * SC_CHUNK + t;
#pragma unroll
        for (int j = 0; j < SC_EPT; j++) {
            int i = base + j * 256;
            if (i < NE) {
                int c = edge_at(e, (long long)NE + i, m);
                if (c >= clo && c < chi) {
                    int r = edge_at(e, (long long)i, m);
                    r = min(max(r, 0), NN - 1);
                    int p = atomicAdd(&cursor[c], 1);
                    edge_t t2; t2.r = r; t2.w = dinv[r];
                    ew[p] = t2;
                }
            }
        }
        return;
    }
    gemm32_body(A, W, Th, (GA_BLOCKS + blockIdx.x) * 32, t, Ws);
}

// ---- per-block reduce of deg -> bsum ----
__global__ __launch_bounds__(256) void k_reduce(const int* __restrict__ deg,
                                                int* __restrict__ bsum) {
    __shared__ int s[256];
    int i = blockIdx.x * 256 + threadIdx.x;
    s[threadIdx.x] = (i < NN) ? deg[i] : 0;
    __syncthreads();
    for (int d = 128; d > 0; d >>= 1) {
        if (threadIdx.x < d) s[threadIdx.x] += s[threadIdx.x + d];
        __syncthreads();
    }
    if (threadIdx.x == 0) bsum[blockIdx.x] = s[0];
}

// ---- apply: block computes its own bsum-prefix, then local scan ----
__global__ __launch_bounds__(256) void k_apply(const int* __restrict__ deg,
                                               const int* __restrict__ bsum,
                                               int* __restrict__ offs,
                                               int* __restrict__ cursor,
                                               float* __restrict__ dinv) {
    __shared__ int s[256];
    __shared__ int base_s;
    int t = threadIdx.x;
    int v = (t < RB && t < blockIdx.x) ? bsum[t] : 0;
    s[t] = v;
    __syncthreads();
    for (int d = 128; d > 0; d >>= 1) {
        if (t < d) s[t] += s[t + d];
        __syncthreads();
    }
    if (t == 0) base_s = s[0];
    __syncthreads();
    int base = base_s;
    __syncthreads();
    int i = blockIdx.x * 256 + t;
    int dg = (i < NN) ? deg[i] : 0;
    s[t] = dg;
    __syncthreads();
    for (int d = 1; d < 256; d <<= 1) {
        int u = (t >= d) ? s[t - d] : 0;
        __syncthreads();
        s[t] += u;
        __syncthreads();
    }
    if (i < NN) {
        int excl = base + s[t] - dg;
        offs[i] = excl;
        cursor[i] = excl;
        dinv[i] = rsqrtf((float)(dg + 1));   // +1 self-loop
        if (i == NN - 1) offs[NN] = excl + dg;
    }
}

// ---- standalone layer-2 GEMM (same 16 KB staging) ----
__global__ __launch_bounds__(256) void k_gemm128h(const float* __restrict__ A,
                                                  const float* __restrict__ W,
                                                  __half* __restrict__ Th) {
    __shared__ float Ws[32 * 128];       // 16 KB
    gemm32_body(A, W, Th, blockIdx.x * 32, threadIdx.x, Ws);
}

// ---- final GEMM with bias: out[N,64] = A[N,128](fp32) @ W[128,64] + b
// W staged in 16 KB k-halves.
__global__ __launch_bounds__(256) void k_gemm64(const float* __restrict__ A,
                                                const float* __restrict__ W,
                                                const float* __restrict__ b,
                                                float* __restrict__ T) {
    __shared__ float Ws[64 * 64];        // 16 KB: one k-half of W
    int t = threadIdx.x;
    int rg = t >> 4, cg = t & 15;
    int row0 = blockIdx.x * 32 + rg * 2;
    const float4* a0 = (const float4*)(A + (long long)min(row0 + 0, NN - 1) * 128);
    const float4* a1 = (const float4*)(A + (long long)min(row0 + 1, NN - 1) * 128);
    float acc[2][4];
#pragma unroll
    for (int i = 0; i < 2; i++)
#pragma unroll
        for (int j = 0; j < 4; j++) acc[i][j] = 0.f;
#pragma unroll
    for (int h = 0; h < 2; h++) {        // 2 k-halves of 64 rows
        __syncthreads();
#pragma unroll
        for (int i = 0; i < 4; i++)
            ((float4*)Ws)[t + 256 * i] = ((const float4*)(W + h * 64 * 64))[t + 256 * i];
        __syncthreads();
#pragma unroll 4
        for (int k4 = 0; k4 < 16; k4++) {
            float4 av0 = a0[h * 16 + k4];
            float4 av1 = a1[h * 16 + k4];
#pragma unroll
            for (int kk = 0; kk < 4; kk++) {
                float4 w = *(const float4*)&Ws[(k4 * 4 + kk) * 64 + cg * 4];
                float x0 = (kk == 0) ? av0.x : (kk == 1) ? av0.y : (kk == 2) ? av0.z : av0.w;
                float x1 = (kk == 0) ? av1.x : (kk == 1) ? av1.y : (kk == 2) ? av1.z : av1.w;
                acc[0][0] += x0 * w.x; acc[0][1] += x0 * w.y;
                acc[0][2] += x0 * w.z; acc[0][3] += x0 * w.w;
                acc[1][0] += x1 * w.x; acc[1][1] += x1 * w.y;
                acc[1][2] += x1 * w.z; acc[1][3] += x1 * w.w;
            }
        }
    }
    float4 bb = ((const float4*)b)[cg];
#pragma unroll
    for (int i = 0; i < 2; i++) {
        int row = row0 + i;
        if (row < NN) {
            float4 v = {acc[i][0] + bb.x, acc[i][1] + bb.y,
                        acc[i][2] + bb.z, acc[i][3] + bb.w};
            *(float4*)&T[(long long)row * 64 + cg * 4] = v;
        }
    }
}

__device__ __forceinline__ float4 h4_to_f4(uint2 u) {
    __half2 h0 = *reinterpret_cast<const __half2*>(&u.x);
    __half2 h1 = *reinterpret_cast<const __half2*>(&u.y);
    float2 f0 = __half22float2(h0);
    float2 f1 = __half22float2(h1);
    float4 r; r.x = f0.x; r.y = f0.y; r.z = f1.x; r.w = f1.y;
    return r;
}

// ---- aggregation: H[c] = relu(dinv[c]*(sum_e w_e*X[src_e] + dinv[c]*X[c]) + b)
// X fp16 (256B rows); fp32 accumulate; one wave per node, two 32-lane halves.
__global__ __launch_bounds__(256) void k_agg_h(const __half* __restrict__ X,
                                               const int* __restrict__ offs,
                                               const edge_t* __restrict__ ew,
                                               const float* __restrict__ dinv,
                                               const float* __restrict__ b,
                                               float* __restrict__ H) {
    int t = threadIdx.x;
    int node = blockIdx.x * 4 + (t >> 6);   // grid exact
    int lane = t & 63;
    int half = lane >> 5, l32 = lane & 31;
    const uint2* X2 = (const uint2*)X;
    float dc = dinv[node];
    float4 acc = {0.f, 0.f, 0.f, 0.f};
    if (half == 0) {
        float4 s = h4_to_f4(X2[(long long)node * 32 + l32]);
        acc.x = dc * s.x; acc.y = dc * s.y; acc.z = dc * s.z; acc.w = dc * s.w;
    }
    int e0 = offs[node], e1 = offs[node + 1];
    int n = e1 - e0;
    const edge_t* ep = ew + e0;
    int i = half;
    for (; i + 6 < n; i += 8) {
        edge_t m0 = ep[i], m1 = ep[i + 2], m2 = ep[i + 4], m3 = ep[i + 6];
        uint2 u0 = X2[(long long)m0.r * 32 + l32];
        uint2 u1 = X2[(long long)m1.r * 32 + l32];
        uint2 u2 = X2[(long long)m2.r * 32 + l32];
        uint2 u3 = X2[(long long)m3.r * 32 + l32];
        float4 v0 = h4_to_f4(u0), v1 = h4_to_f4(u1);
        float4 v2 = h4_to_f4(u2), v3 = h4_to_f4(u3);
        acc.x += m0.w * v0.x + m1.w * v1.x + m2.w * v2.x + m3.w * v3.x;
        acc.y += m0.w * v0.y + m1.w * v1.y + m2.w * v2.y + m3.w * v3.y;
        acc.z += m0.w * v0.z + m1.w * v1.z + m2.w * v2.z + m3.w * v3.z;
        acc.w += m0.w * v0.w + m1.w * v1.w + m2.w * v2.w + m3.w * v3.w;
    }
    for (; i < n; i += 2) {
        edge_t m = ep[i];
        float4 v = h4_to_f4(X2[(long long)m.r * 32 + l32]);
        acc.x += m.w * v.x; acc.y += m.w * v.y;
        acc.z += m.w * v.z; acc.w += m.w * v.w;
    }
    float4 oth;
    oth.x = __shfl_xor(acc.x, 32);
    oth.y = __shfl_xor(acc.y, 32);
    oth.z = __shfl_xor(acc.z, 32);
    oth.w = __shfl_xor(acc.w, 32);
    float4 bb = ((const float4*)b)[l32];
    float4 o;
    o.x = fmaxf(dc * (acc.x + oth.x) + bb.x, 0.f);
    o.y = fmaxf(dc * (acc.y + oth.y) + bb.y, 0.f);
    o.z = fmaxf(dc * (acc.z + oth.z) + bb.z, 0.f);
    o.w = fmaxf(dc * (acc.w + oth.w) + bb.w, 0.f);
    if (half == 0)
        ((float4*)H)[(long long)node * 32 + l32] = o;
}

extern "C" void kernel_launch(void* const* d_in, const int* in_sizes, int n_in,
                              void* d_out, int out_size, void* d_ws, size_t ws_size,
                              hipStream_t stream) {
    const float* x  = (const float*)d_in[0];
    const void*  ei = d_in[1];
    const float* W1 = (const float*)d_in[2];
    const float* b1 = (const float*)d_in[3];
    const float* W2 = (const float*)d_in[4];
    const float* b2 = (const float*)d_in[5];
    const float* Wl = (const float*)d_in[6];
    const float* bl = (const float*)d_in[7];
    float* out = (float*)d_out;

    char* ws = (char*)d_ws;
    size_t off = 0;
    auto alloc = [&](size_t bytes) {
        void* p = ws + off;
        off += (bytes + 255) & ~(size_t)255;
        return p;
    };
    __half* t0h    = (__half*)alloc((size_t)NN * 128 * 2);  // fp16 staged (reused layer2)
    float*  t1     = (float*)alloc((size_t)NN * 128 * 4);   // fp32 agg out (reused layer2)
    int*    deg    = (int*)alloc((size_t)NN * 4);
    int*    offs   = (int*)alloc((size_t)(NN + 1) * 4);
    int*    cursor = (int*)alloc((size_t)NN * 4);
    edge_t* ewbuf  = (edge_t*)alloc((size_t)NE * 8);
    float*  dinv   = (float*)alloc((size_t)NN * 4);
    int*    bsum   = (int*)alloc((size_t)RB * 4);

    hipMemsetAsync(deg, 0, (size_t)NN * 4, stream);
    // A: gemm1 first half + count
    k_gemm_count<<<GA_BLOCKS + SC_CHUNKS * SC_GROUPS, 256, 0, stream>>>(ei, deg, x, W1, t0h);
    k_reduce<<<RB, 256, 0, stream>>>(deg, bsum);
    k_apply<<<RB, 256, 0, stream>>>(deg, bsum, offs, cursor, dinv);
    // B: gemm1 second half + scatter
    k_gemm_scatter<<<GB_BLOCKS + SC_CHUNKS * SC_GROUPS, 256, 0, stream>>>(
        ei, cursor, ewbuf, dinv, x, W1, t0h);

    k_agg_h<<<NN / 4, 256, 0, stream>>>(t0h, offs, ewbuf, dinv, b1, t1);
    k_gemm128h<<<GB32, 256, 0, stream>>>(t1, W2, t0h);
    k_agg_h<<<NN / 4, 256, 0, stream>>>(t0h, offs, ewbuf, dinv, b2, t1);
    k_gemm64<<<GB32, 256, 0, stream>>>(t1, Wl, bl, out);
}

// Round 14
// 283.600 us; speedup vs baseline: 1.0451x; 1.0451x over previous
//
#include <hip/hip_runtime.h>
#include <hip/hip_fp16.h>

#define NN 50000
#define NE 640000
#define RB ((NN + 255) / 256)   // 196 scan blocks
#define GB32 ((NN + 31) / 32)   // 1563 gemm blocks

#define SC_GROUPS 8              // destination-range groups (~XCDs via blockIdx%8)
#define SC_RANGE (NN / SC_GROUPS)        // 6250
#define SC_EPT 8                 // edges per thread
#define SC_CHUNK (256 * SC_EPT)          // 2048 edges per block-chunk
#define SC_CHUNKS ((NE + SC_CHUNK - 1) / SC_CHUNK)

struct __align__(8) edge_t { int r; float w; };

__device__ __forceinline__ int edge_at(const void* p, long long i, int m64) {
    if (m64) return (int)((const long long*)p)[i];
    return ((const int*)p)[i];
}

// per-block int64/int32 detection: odd words are int64 high words (zero for
// nonneg < 2^31) or int32 row values (random nonzero w.h.p.)
__device__ __forceinline__ int detect_m64(const unsigned* w, int tid) {
    __shared__ int found;
    if (tid == 0) found = 0;
    __syncthreads();
    if (tid < 256 && w[2 * tid + 1] != 0u) atomicAdd(&found, 1);
    __syncthreads();
    return (found == 0) ? 1 : 0;
}

// ---- FUSED (R12 structure): blocks [0,GB32) = gemm1 (x@W1 -> fp16);
// blocks [GB32,..) = XCD-localized in-degree count, now ALSO recording each
// edge's within-node rank (the atomic's return value) for atomic-free scatter.
__global__ __launch_bounds__(256) void k_count_gemm(const void* __restrict__ e,
                                                    int* __restrict__ deg,
                                                    int* __restrict__ rank,
                                                    const float* __restrict__ A,
                                                    const float* __restrict__ W,
                                                    __half* __restrict__ Th) {
    __shared__ float Ws[64 * 128];           // 32 KB (gemm path)
    int t = threadIdx.x;
    if (blockIdx.x >= GB32) {
        // ---- count path ----
        int m = detect_m64((const unsigned*)e, t);
        int b = blockIdx.x - GB32;
        int g = b & (SC_GROUPS - 1);
        int chunk = b >> 3;
        int clo = g * SC_RANGE, chi = clo + SC_RANGE;
        int base = chunk * SC_CHUNK + t;
#pragma unroll
        for (int j = 0; j < SC_EPT; j++) {
            int i = base + j * 256;
            if (i < NE) {
                int c = edge_at(e, (long long)NE + i, m);
                if (c >= clo && c < chi)
                    rank[i] = atomicAdd(&deg[c], 1);
            }
        }
        return;
    }
    // ---- gemm path: 32 rows/block, W staged in LDS halves, 2x8 tile ----
    int rg = t >> 4, cg = t & 15;
    int row0 = blockIdx.x * 32 + rg * 2;
    const float4* a0 = (const float4*)(A + (long long)min(row0 + 0, NN - 1) * 128);
    const float4* a1 = (const float4*)(A + (long long)min(row0 + 1, NN - 1) * 128);
    float acc[2][8];
#pragma unroll
    for (int i = 0; i < 2; i++)
#pragma unroll
        for (int j = 0; j < 8; j++) acc[i][j] = 0.f;
#pragma unroll
    for (int h = 0; h < 2; h++) {
        __syncthreads();
#pragma unroll
        for (int i = 0; i < 8; i++)
            ((float4*)Ws)[t + 256 * i] = ((const float4*)(W + h * 64 * 128))[t + 256 * i];
        __syncthreads();
#pragma unroll 4
        for (int k4 = 0; k4 < 16; k4++) {
            float4 av0 = a0[h * 16 + k4];
            float4 av1 = a1[h * 16 + k4];
#pragma unroll
            for (int kk = 0; kk < 4; kk++) {
                float4 w0 = *(const float4*)&Ws[(k4 * 4 + kk) * 128 + cg * 4];
                float4 w1 = *(const float4*)&Ws[(k4 * 4 + kk) * 128 + cg * 4 + 64];
                float x0 = (kk == 0) ? av0.x : (kk == 1) ? av0.y : (kk == 2) ? av0.z : av0.w;
                float x1 = (kk == 0) ? av1.x : (kk == 1) ? av1.y : (kk == 2) ? av1.z : av1.w;
                acc[0][0] += x0 * w0.x; acc[0][1] += x0 * w0.y;
                acc[0][2] += x0 * w0.z; acc[0][3] += x0 * w0.w;
                acc[0][4] += x0 * w1.x; acc[0][5] += x0 * w1.y;
                acc[0][6] += x0 * w1.z; acc[0][7] += x0 * w1.w;
                acc[1][0] += x1 * w0.x; acc[1][1] += x1 * w0.y;
                acc[1][2] += x1 * w0.z; acc[1][3] += x1 * w0.w;
                acc[1][4] += x1 * w1.x; acc[1][5] += x1 * w1.y;
                acc[1][6] += x1 * w1.z; acc[1][7] += x1 * w1.w;
            }
        }
    }
#pragma unroll
    for (int i = 0; i < 2; i++) {
        int row = row0 + i;
        if (row < NN) {
            __half2 p0 = __floats2half2_rn(acc[i][0], acc[i][1]);
            __half2 p1 = __floats2half2_rn(acc[i][2], acc[i][3]);
            __half2 p2 = __floats2half2_rn(acc[i][4], acc[i][5]);
            __half2 p3 = __floats2half2_rn(acc[i][6], acc[i][7]);
            uint2 u0; u0.x = *(unsigned*)&p0; u0.y = *(unsigned*)&p1;
            uint2 u1; u1.x = *(unsigned*)&p2; u1.y = *(unsigned*)&p3;
            *(uint2*)(Th + (long long)row * 128 + cg * 4) = u0;
            *(uint2*)(Th + (long long)row * 128 + cg * 4 + 64) = u1;
        }
    }
}

// ---- per-block reduce of deg -> bsum ----
__global__ __launch_bounds__(256) void k_reduce(const int* __restrict__ deg,
                                                int* __restrict__ bsum) {
    __shared__ int s[256];
    int i = blockIdx.x * 256 + threadIdx.x;
    s[threadIdx.x] = (i < NN) ? deg[i] : 0;
    __syncthreads();
    for (int d = 128; d > 0; d >>= 1) {
        if (threadIdx.x < d) s[threadIdx.x] += s[threadIdx.x + d];
        __syncthreads();
    }
    if (threadIdx.x == 0) bsum[blockIdx.x] = s[0];
}

// ---- apply: block computes its own bsum-prefix, then local scan ----
__global__ __launch_bounds__(256) void k_apply(const int* __restrict__ deg,
                                               const int* __restrict__ bsum,
                                               int* __restrict__ offs,
                                               float* __restrict__ dinv) {
    __shared__ int s[256];
    __shared__ int base_s;
    int t = threadIdx.x;
    int v = (t < RB && t < blockIdx.x) ? bsum[t] : 0;
    s[t] = v;
    __syncthreads();
    for (int d = 128; d > 0; d >>= 1) {
        if (t < d) s[t] += s[t + d];
        __syncthreads();
    }
    if (t == 0) base_s = s[0];
    __syncthreads();
    int base = base_s;
    __syncthreads();
    int i = blockIdx.x * 256 + t;
    int dg = (i < NN) ? deg[i] : 0;
    s[t] = dg;
    __syncthreads();
    for (int d = 1; d < 256; d <<= 1) {
        int u = (t >= d) ? s[t - d] : 0;
        __syncthreads();
        s[t] += u;
        __syncthreads();
    }
    if (i < NN) {
        int excl = base + s[t] - dg;
        offs[i] = excl;
        dinv[i] = rsqrtf((float)(dg + 1));   // +1 self-loop
        if (i == NN - 1) offs[NN] = excl + dg;
    }
}

// ---- scatter, XCD-localized, ATOMIC-FREE: p = offs[c] + rank[i] ----
__global__ __launch_bounds__(256) void k_scatter(const void* __restrict__ e,
                                                 const int* __restrict__ offs,
                                                 const int* __restrict__ rank,
                                                 edge_t* __restrict__ ew,
                                                 const float* __restrict__ dinv) {
    int m = detect_m64((const unsigned*)e, threadIdx.x);
    int b = blockIdx.x;
    int g = b & (SC_GROUPS - 1);
    int chunk = b >> 3;
    int clo = g * SC_RANGE, chi = clo + SC_RANGE;
    int base = chunk * SC_CHUNK + threadIdx.x;
#pragma unroll
    for (int j = 0; j < SC_EPT; j++) {
        int i = base + j * 256;
        if (i < NE) {
            int c = edge_at(e, (long long)NE + i, m);
            if (c >= clo && c < chi) {
                int r = edge_at(e, (long long)i, m);
                r = min(max(r, 0), NN - 1);
                int p = offs[c] + rank[i];
                edge_t t2; t2.r = r; t2.w = dinv[r];
                ew[p] = t2;
            }
        }
    }
}

// ---- standalone layer-2 GEMM (32 KB staging, R12-proven) ----
__global__ __launch_bounds__(256) void k_gemm128h(const float* __restrict__ A,
                                                  const float* __restrict__ W,
                                                  __half* __restrict__ Th) {
    __shared__ float Ws[64 * 128];           // 32 KB: one K-half of W
    int t = threadIdx.x;
    int rg = t >> 4, cg = t & 15;
    int row0 = blockIdx.x * 32 + rg * 2;
    const float4* a0 = (const float4*)(A + (long long)min(row0 + 0, NN - 1) * 128);
    const float4* a1 = (const float4*)(A + (long long)min(row0 + 1, NN - 1) * 128);
    float acc[2][8];
#pragma unroll
    for (int i = 0; i < 2; i++)
#pragma unroll
        for (int j = 0; j < 8; j++) acc[i][j] = 0.f;
#pragma unroll
    for (int h = 0; h < 2; h++) {
        __syncthreads();
#pragma unroll
        for (int i = 0; i < 8; i++)
            ((float4*)Ws)[t + 256 * i] = ((const float4*)(W + h * 64 * 128))[t + 256 * i];
        __syncthreads();
#pragma unroll 4
        for (int k4 = 0; k4 < 16; k4++) {
            float4 av0 = a0[h * 16 + k4];
            float4 av1 = a1[h * 16 + k4];
#pragma unroll
            for (int kk = 0; kk < 4; kk++) {
                float4 w0 = *(const float4*)&Ws[(k4 * 4 + kk) * 128 + cg * 4];
                float4 w1 = *(const float4*)&Ws[(k4 * 4 + kk) * 128 + cg * 4 + 64];
                float x0 = (kk == 0) ? av0.x : (kk == 1) ? av0.y : (kk == 2) ? av0.z : av0.w;
                float x1 = (kk == 0) ? av1.x : (kk == 1) ? av1.y : (kk == 2) ? av1.z : av1.w;
                acc[0][0] += x0 * w0.x; acc[0][1] += x0 * w0.y;
                acc[0][2] += x0 * w0.z; acc[0][3] += x0 * w0.w;
                acc[0][4] += x0 * w1.x; acc[0][5] += x0 * w1.y;
                acc[0][6] += x0 * w1.z; acc[0][7] += x0 * w1.w;
                acc[1][0] += x1 * w0.x; acc[1][1] += x1 * w0.y;
                acc[1][2] += x1 * w0.z; acc[1][3] += x1 * w0.w;
                acc[1][4] += x1 * w1.x; acc[1][5] += x1 * w1.y;
                acc[1][6] += x1 * w1.z; acc[1][7] += x1 * w1.w;
            }
        }
    }
#pragma unroll
    for (int i = 0; i < 2; i++) {
        int row = row0 + i;
        if (row < NN) {
            __half2 p0 = __floats2half2_rn(acc[i][0], acc[i][1]);
            __half2 p1 = __floats2half2_rn(acc[i][2], acc[i][3]);
            __half2 p2 = __floats2half2_rn(acc[i][4], acc[i][5]);
            __half2 p3 = __floats2half2_rn(acc[i][6], acc[i][7]);
            uint2 u0; u0.x = *(unsigned*)&p0; u0.y = *(unsigned*)&p1;
            uint2 u1; u1.x = *(unsigned*)&p2; u1.y = *(unsigned*)&p3;
            *(uint2*)(Th + (long long)row * 128 + cg * 4) = u0;
            *(uint2*)(Th + (long long)row * 128 + cg * 4 + 64) = u1;
        }
    }
}

// ---- final GEMM with bias: out[N,64] = A[N,128](fp32) @ W[128,64] + b ----
__global__ __launch_bounds__(256) void k_gemm64(const float* __restrict__ A,
                                                const float* __restrict__ W,
                                                const float* __restrict__ b,
                                                float* __restrict__ T) {
    __shared__ float Ws[128 * 64];           // 32 KB
    int t = threadIdx.x;
#pragma unroll
    for (int i = 0; i < 8; i++)
        ((float4*)Ws)[t + 256 * i] = ((const float4*)W)[t + 256 * i];
    __syncthreads();
    int rg = t >> 4, cg = t & 15;
    int row0 = blockIdx.x * 32 + rg * 2;
    const float4* a0 = (const float4*)(A + (long long)min(row0 + 0, NN - 1) * 128);
    const float4* a1 = (const float4*)(A + (long long)min(row0 + 1, NN - 1) * 128);
    float acc[2][4];
#pragma unroll
    for (int i = 0; i < 2; i++)
#pragma unroll
        for (int j = 0; j < 4; j++) acc[i][j] = 0.f;
#pragma unroll 4
    for (int k4 = 0; k4 < 32; k4++) {
        float4 av0 = a0[k4];
        float4 av1 = a1[k4];
#pragma unroll
        for (int kk = 0; kk < 4; kk++) {
            float4 w = *(const float4*)&Ws[(k4 * 4 + kk) * 64 + cg * 4];
            float x0 = (kk == 0) ? av0.x : (kk == 1) ? av0.y : (kk == 2) ? av0.z : av0.w;
            float x1 = (kk == 0) ? av1.x : (kk == 1) ? av1.y : (kk == 2) ? av1.z : av1.w;
            acc[0][0] += x0 * w.x; acc[0][1] += x0 * w.y;
            acc[0][2] += x0 * w.z; acc[0][3] += x0 * w.w;
            acc[1][0] += x1 * w.x; acc[1][1] += x1 * w.y;
            acc[1][2] += x1 * w.z; acc[1][3] += x1 * w.w;
        }
    }
    float4 bb = ((const float4*)b)[cg];
#pragma unroll
    for (int i = 0; i < 2; i++) {
        int row = row0 + i;
        if (row < NN) {
            float4 v = {acc[i][0] + bb.x, acc[i][1] + bb.y,
                        acc[i][2] + bb.z, acc[i][3] + bb.w};
            *(float4*)&T[(long long)row * 64 + cg * 4] = v;
        }
    }
}

__device__ __forceinline__ float4 h4_to_f4(uint2 u) {
    __half2 h0 = *reinterpret_cast<const __half2*>(&u.x);
    __half2 h1 = *reinterpret_cast<const __half2*>(&u.y);
    float2 f0 = __half22float2(h0);
    float2 f1 = __half22float2(h1);
    float4 r; r.x = f0.x; r.y = f0.y; r.z = f1.x; r.w = f1.y;
    return r;
}

// ---- aggregation: H[c] = relu(dinv[c]*(sum_e w_e*X[src_e] + dinv[c]*X[c]) + b)
// X fp16 (256B rows); fp32 accumulate; one wave per node, two 32-lane halves.
__global__ __launch_bounds__(256) void k_agg_h(const __half* __restrict__ X,
                                               const int* __restrict__ offs,
                                               const edge_t* __restrict__ ew,
                                               const float* __restrict__ dinv,
                                               const float* __restrict__ b,
                                               float* __restrict__ H) {
    int t = threadIdx.x;
    int node = blockIdx.x * 4 + (t >> 6);   // grid exact
    int lane = t & 63;
    int half = lane >> 5, l32 = lane & 31;
    const uint2* X2 = (const uint2*)X;
    float dc = dinv[node];
    float4 acc = {0.f, 0.f, 0.f, 0.f};
    if (half == 0) {
        float4 s = h4_to_f4(X2[(long long)node * 32 + l32]);
        acc.x = dc * s.x; acc.y = dc * s.y; acc.z = dc * s.z; acc.w = dc * s.w;
    }
    int e0 = offs[node], e1 = offs[node + 1];
    int n = e1 - e0;
    const edge_t* ep = ew + e0;
    int i = half;
    for (; i + 6 < n; i += 8) {
        edge_t m0 = ep[i], m1 = ep[i + 2], m2 = ep[i + 4], m3 = ep[i + 6];
        uint2 u0 = X2[(long long)m0.r * 32 + l32];
        uint2 u1 = X2[(long long)m1.r * 32 + l32];
        uint2 u2 = X2[(long long)m2.r * 32 + l32];
        uint2 u3 = X2[(long long)m3.r * 32 + l32];
        float4 v0 = h4_to_f4(u0), v1 = h4_to_f4(u1);
        float4 v2 = h4_to_f4(u2), v3 = h4_to_f4(u3);
        acc.x += m0.w * v0.x + m1.w * v1.x + m2.w * v2.x + m3.w * v3.x;
        acc.y += m0.w * v0.y + m1.w * v1.y + m2.w * v2.y + m3.w * v3.y;
        acc.z += m0.w * v0.z + m1.w * v1.z + m2.w * v2.z + m3.w * v3.z;
        acc.w += m0.w * v0.w + m1.w * v1.w + m2.w * v2.w + m3.w * v3.w;
    }
    for (; i < n; i += 2) {
        edge_t m = ep[i];
        float4 v = h4_to_f4(X2[(long long)m.r * 32 + l32]);
        acc.x += m.w * v.x; acc.y += m.w * v.y;
        acc.z += m.w * v.z; acc.w += m.w * v.w;
    }
    float4 oth;
    oth.x = __shfl_xor(acc.x, 32);
    oth.y = __shfl_xor(acc.y, 32);
    oth.z = __shfl_xor(acc.z, 32);
    oth.w = __shfl_xor(acc.w, 32);
    float4 bb = ((const float4*)b)[l32];
    float4 o;
    o.x = fmaxf(dc * (acc.x + oth.x) + bb.x, 0.f);
    o.y = fmaxf(dc * (acc.y + oth.y) + bb.y, 0.f);
    o.z = fmaxf(dc * (acc.z + oth.z) + bb.z, 0.f);
    o.w = fmaxf(dc * (acc.w + oth.w) + bb.w, 0.f);
    if (half == 0)
        ((float4*)H)[(long long)node * 32 + l32] = o;
}

extern "C" void kernel_launch(void* const* d_in, const int* in_sizes, int n_in,
                              void* d_out, int out_size, void* d_ws, size_t ws_size,
                              hipStream_t stream) {
    const float* x  = (const float*)d_in[0];
    const void*  ei = d_in[1];
    const float* W1 = (const float*)d_in[2];
    const float* b1 = (const float*)d_in[3];
    const float* W2 = (const float*)d_in[4];
    const float* b2 = (const float*)d_in[5];
    const float* Wl = (const float*)d_in[6];
    const float* bl = (const float*)d_in[7];
    float* out = (float*)d_out;

    char* ws = (char*)d_ws;
    size_t off = 0;
    auto alloc = [&](size_t bytes) {
        void* p = ws + off;
        off += (bytes + 255) & ~(size_t)255;
        return p;
    };
    __half* t0h    = (__half*)alloc((size_t)NN * 128 * 2);  // fp16 staged (reused layer2)
    float*  t1     = (float*)alloc((size_t)NN * 128 * 4);   // fp32 agg out (reused layer2)
    int*    deg    = (int*)alloc((size_t)NN * 4);
    int*    offs   = (int*)alloc((size_t)(NN + 1) * 4);
    int*    rank   = (int*)alloc((size_t)NE * 4);
    edge_t* ewbuf  = (edge_t*)alloc((size_t)NE * 8);
    float*  dinv   = (float*)alloc((size_t)NN * 4);
    int*    bsum   = (int*)alloc((size_t)RB * 4);

    hipMemsetAsync(deg, 0, (size_t)NN * 4, stream);
    // fused (R12 structure): gemm1 + count-with-rank
    k_count_gemm<<<GB32 + SC_CHUNKS * SC_GROUPS, 256, 0, stream>>>(ei, deg, rank, x, W1, t0h);
    k_reduce<<<RB, 256, 0, stream>>>(deg, bsum);
    k_apply<<<RB, 256, 0, stream>>>(deg, bsum, offs, dinv);
    k_scatter<<<SC_CHUNKS * SC_GROUPS, 256, 0, stream>>>(ei, offs, rank, ewbuf, dinv);

    k_agg_h<<<NN / 4, 256, 0, stream>>>(t0h, offs, ewbuf, dinv, b1, t1);
    k_gemm128h<<<GB32, 256, 0, stream>>>(t1, W2, t0h);
    k_agg_h<<<NN / 4, 256, 0, stream>>>(t0h, offs, ewbuf, dinv, b2, t1);
    k_gemm64<<<GB32, 256, 0, stream>>>(t1, Wl, bl, out);
}